// Round 7
// baseline (397.832 us; speedup 1.0000x reference)
//
#include <hip/hip_runtime.h>
#include <math.h>

#define N_USERS 50000
#define N_ENT   200000
#define NTOT    250000
#define D       128
#define E_EDGES 2000000
#define B       8192
#define NCAT    8
#define NNUM    16
#define CAP     64     // per-slot edge bin capacity (Poisson(8) degree; P(>64)~1e-38)
#define NBLK    1024   // exactly 4 blocks/CU x 256 CUs -> guaranteed co-resident
#define NTHR    256
#define GTHREADS (NBLK * NTHR)

typedef __attribute__((ext_vector_type(4))) float f32x4;
typedef __attribute__((ext_vector_type(8))) short short8;

__device__ __forceinline__ float sigf(float x) { return 1.0f / (1.0f + expf(-x)); }

__device__ __forceinline__ short f2bf(float f) {
    unsigned u = __float_as_uint(f);
    unsigned r = (u + 0x7FFF + ((u >> 16) & 1)) >> 16;
    return (short)r;
}
__device__ __forceinline__ unsigned pack_bf2(float lo, float hi) {
    return ((unsigned)(unsigned short)f2bf(hi) << 16) | (unsigned short)f2bf(lo);
}
__device__ __forceinline__ float bf_lo(unsigned x) { return __uint_as_float(x << 16); }
__device__ __forceinline__ float bf_hi(unsigned x) { return __uint_as_float(x & 0xFFFF0000u); }
__device__ __forceinline__ float dot4(float4 a, float4 b) {
    return a.x * b.x + a.y * b.y + a.z * b.z + a.w * b.w;
}

// ---------------------------------------------------------------------------
// Two-level device-scope grid barrier. 32 groups of 32 blocks: arrivals
// serialize <=32-deep per counter (avoids the single-address atomic wall).
// AGENT-scope acq_rel atomics emit the L2 writeback/invalidate needed for
// cross-XCD visibility on gfx950.
__device__ __forceinline__ void grid_barrier(int* __restrict__ grp,
                                             int* __restrict__ root, int phase) {
    __syncthreads();
    if (threadIdx.x == 0) {
        const int g = blockIdx.x >> 5;   // 32 blocks per group
        int r = __hip_atomic_fetch_add(&grp[phase * 32 + g], 1,
                                       __ATOMIC_ACQ_REL, __HIP_MEMORY_SCOPE_AGENT);
        if (r == 31)
            __hip_atomic_fetch_add(&root[phase * 16], 1,
                                   __ATOMIC_ACQ_REL, __HIP_MEMORY_SCOPE_AGENT);
        while (__hip_atomic_load(&root[phase * 16],
                                 __ATOMIC_ACQUIRE, __HIP_MEMORY_SCOPE_AGENT) < 32)
            __builtin_amdgcn_s_sleep(4);
    }
    __syncthreads();
}

// ---------------------------------------------------------------------------
__global__ __launch_bounds__(NTHR, 4) void mega_kernel(
    int* __restrict__ bars,                 // [4*32 grp | 4*16 root]
    int* __restrict__ map, int* __restrict__ bincnt, int2* __restrict__ bins,
    short* __restrict__ W0h, short* __restrict__ W1h,
    float* __restrict__ w2eff, float* __restrict__ beff0,
    float* __restrict__ beff1, float* __restrict__ b2eff,
    unsigned short* __restrict__ Xu, unsigned short* __restrict__ Xi,
    const float* __restrict__ embed,
    const float* __restrict__ u_tab, const float* __restrict__ i_tab,
    const float* __restrict__ numW_u, const float* __restrict__ numb_u,
    const float* __restrict__ numW_i, const float* __restrict__ numb_i,
    const float* __restrict__ W0, const float* __restrict__ b0,
    const float* __restrict__ Mw0, const float* __restrict__ Mb0,
    const float* __restrict__ W1, const float* __restrict__ b1,
    const float* __restrict__ Mw1, const float* __restrict__ Mb1,
    const float* __restrict__ W2, const float* __restrict__ b2,
    const float* __restrict__ Mw2, const float* __restrict__ Mb2,
    const float* __restrict__ u_numf, const float* __restrict__ i_numf,
    const int* __restrict__ A_rows, const int* __restrict__ A_cols,
    const float* __restrict__ A_vals,
    const int* __restrict__ u_catf, const int* __restrict__ i_catf,
    const int* __restrict__ uids, const int* __restrict__ iids,
    float* __restrict__ out)
{
    int* grp  = bars;
    int* root = bars + 128;
    const int tid  = threadIdx.x;
    const int gtid = blockIdx.x * NTHR + tid;

    __shared__ __align__(16) short XsE[2 * 16 * 256];   // 16KB: Xu/Xi tiles (phase E)
    __shared__ __align__(16) short Hs[16 * 256];        // 8KB: H0 tile
    __shared__ float gsum[4][16];
    __shared__ float w_s[2][16];

    // ================= Phase A: init map/bincnt + effective weights ========
    for (int t = gtid; t < 330278; t += GTHREADS) {
        if (t < 62500) {
            ((int4*)map)[t] = make_int4(-1, -1, -1, -1);
        } else if (t < 66596) {
            ((int4*)bincnt)[t - 62500] = make_int4(0, 0, 0, 0);
        } else {
            const int i = t - 66596;
            if (i < 131072) {
                W0h[i] = f2bf(W0[i & 65535] * sigf(Mw0[i]));
            } else if (i < 262144) {
                const int ii = i - 131072;
                W1h[ii] = f2bf(W1[ii & 65535] * sigf(Mw1[ii]));
            } else if (i < 262656) {
                const int ii = i - 262144;
                w2eff[ii] = W2[ii & 255] * sigf(Mw2[ii]);
            } else if (i < 263168) {
                const int ii = i - 262656;
                beff0[ii] = b0[ii & 255] * sigf(Mb0[ii]);
            } else if (i < 263680) {
                const int ii = i - 263168;
                beff1[ii] = b1[ii & 255] * sigf(Mb1[ii]);
            } else if (i < 263682) {
                const int ii = i - 263680;
                b2eff[ii] = b2[0] * sigf(Mb2[ii]);
            }
        }
    }
    grid_barrier(grp, root, 0);

    // ================= Phase B: row -> slot map ============================
    if (gtid < B) {
        atomicMax(&map[uids[gtid] + N_ENT], gtid);
        atomicMax(&map[iids[gtid]], B + gtid);
    }
    grid_barrier(grp, root, 1);

    // ================= Phase C: edge scatter into per-slot bins ============
    for (int g = gtid; g < E_EDGES / 2; g += GTHREADS) {
        const int2 rr = *(const int2*)(A_rows + 2 * g);
        const int s0 = map[rr.x];
        const int s1 = map[rr.y];
        if (s0 >= 0) {
            const int p = atomicAdd(&bincnt[s0], 1);
            if (p < CAP)
                bins[(size_t)s0 * CAP + p] = make_int2(A_cols[2 * g], __float_as_int(A_vals[2 * g]));
        }
        if (s1 >= 0) {
            const int p = atomicAdd(&bincnt[s1], 1);
            if (p < CAP)
                bins[(size_t)s1 * CAP + p] = make_int2(A_cols[2 * g + 1], __float_as_int(A_vals[2 * g + 1]));
        }
    }
    grid_barrier(grp, root, 2);

    // ================= Phase D: neighbor-gather + feature build ============
    {
        const int lane = tid & 63;
        const int wid0 = gtid >> 6;            // 0..4095
        const int d2   = lane * 2;
        for (int task = wid0; task < 2 * B; task += (GTHREADS >> 6)) {
            const int side = task & 1;
            const int b    = task >> 1;
            const int* ids = side ? iids : uids;
            const int* cat_feats = side ? i_catf : u_catf;
            const float* num_feats = side ? i_numf : u_numf;
            const float* cat_table = side ? i_tab : u_tab;
            const float* numW = side ? numW_i : numW_u;
            const float* numb = side ? numb_i : numb_u;
            unsigned short* Xo = side ? Xi : Xu;

            const int uid  = __builtin_amdgcn_readfirstlane(ids[b]);
            const int grow = uid + (side ? 0 : N_ENT);
            const int slot = __builtin_amdgcn_readfirstlane(map[grow]);
            const int n    = min(__builtin_amdgcn_readfirstlane(bincnt[slot]), CAP);

            const float2 ev0 = *(const float2*)(embed + (size_t)grow * D + d2);
            const int4* bl4 = (const int4*)(bins + (size_t)slot * CAP);
            const int4 ea = bl4[0], eb = bl4[1], ec = bl4[2], ed = bl4[3];
            const int4 cf0 = *(const int4*)(cat_feats + uid * NCAT);
            const int4 cf1 = *(const int4*)(cat_feats + uid * NCAT + 4);
            const float4* nf = (const float4*)(num_feats + (size_t)uid * NNUM);
            const float4 f0 = nf[0], f1 = nf[1], f2v = nf[2], f3 = nf[3];
            const float2 nbv = *(const float2*)(numb + d2);

            float gx = 0.f, gy = 0.f;
            {
                int cc[8]; float vv[8];
                cc[0]=ea.x; vv[0]=__int_as_float(ea.y); cc[1]=ea.z; vv[1]=__int_as_float(ea.w);
                cc[2]=eb.x; vv[2]=__int_as_float(eb.y); cc[3]=eb.z; vv[3]=__int_as_float(eb.w);
                cc[4]=ec.x; vv[4]=__int_as_float(ec.y); cc[5]=ec.z; vv[5]=__int_as_float(ec.w);
                cc[6]=ed.x; vv[6]=__int_as_float(ed.y); cc[7]=ed.z; vv[7]=__int_as_float(ed.w);
                float2 r[8];
#pragma unroll
                for (int j = 0; j < 8; ++j) {
                    const int c = (j < n) ? cc[j] : 0;
                    r[j] = *(const float2*)(embed + (size_t)c * D + d2);
                }
#pragma unroll
                for (int j = 0; j < 8; ++j) {
                    const float v = (j < n) ? vv[j] : 0.f;
                    gx += v * r[j].x;
                    gy += v * r[j].y;
                }
            }
            const int2* bl = bins + (size_t)slot * CAP;
            for (int j = 8; j < n; j += 2) {
                const int2 c0 = bl[j];
                const bool has1 = (j + 1 < n);
                const int2 c1 = has1 ? bl[j + 1] : make_int2(0, 0);
                const float2 r0 = *(const float2*)(embed + (size_t)c0.x * D + d2);
                const float2 r1 = *(const float2*)(embed + (size_t)c1.x * D + d2);
                const float v0 = __int_as_float(c0.y);
                const float v1 = has1 ? __int_as_float(c1.y) : 0.f;
                gx += v0 * r0.x + v1 * r1.x;
                gy += v0 * r0.y + v1 * r1.y;
            }

            int cid[8] = {cf0.x, cf0.y, cf0.z, cf0.w, cf1.x, cf1.y, cf1.z, cf1.w};
            int cnt = 0;
#pragma unroll
            for (int f = 0; f < 8; ++f) cnt += (cid[f] > 0);
            float2 ct[8];
#pragma unroll
            for (int f = 0; f < 8; ++f)
                ct[f] = *(const float2*)(cat_table + (size_t)cid[f] * D + d2);
            float csx = 0.f, csy = 0.f;
#pragma unroll
            for (int f = 0; f < 8; ++f) { csx += ct[f].x; csy += ct[f].y; }
            const float inv = (cnt > 0) ? (1.0f / (float)cnt) : 0.0f;

            const float4* w0r = (const float4*)(numW + (size_t)d2 * NNUM);
            const float4* w1r = (const float4*)(numW + (size_t)(d2 + 1) * NNUM);
            float na  = nbv.x + dot4(w0r[0], f0) + dot4(w0r[1], f1) + dot4(w0r[2], f2v) + dot4(w0r[3], f3);
            float nb_ = nbv.y + dot4(w1r[0], f0) + dot4(w1r[1], f1) + dot4(w1r[2], f2v) + dot4(w1r[3], f3);

            const float fx = csx * inv + fmaxf(na, 0.f);
            const float fy = csy * inv + fmaxf(nb_, 0.f);

            unsigned short* row = Xo + (size_t)b * 256;
            *(unsigned*)(row + d2)       = pack_bf2(ev0.x + gx, ev0.y + gy);
            *(unsigned*)(row + 128 + d2) = pack_bf2(fx, fy);
        }
    }
    grid_barrier(grp, root, 3);

    // ================= Phase E: MLP (both sides) + gate + fused dot ========
    // Block t: rows [t*16, t*16+16), both sides. 512 active blocks.
    if (blockIdx.x < B / 16) {
        const int r0 = blockIdx.x * 16;
        const int w = tid >> 6, l = tid & 63, l15 = l & 15, l4 = l >> 4;

        // stage both X tiles (bf16, XOR-swizzled)
#pragma unroll
        for (int i = 0; i < 4; ++i) {
            const int ch   = tid + i * 256;        // 0..1023
            const int side = ch >> 9;
            const int c    = ch & 511;
            const int row  = c >> 5;
            const int c8   = (c & 31) << 3;
            const unsigned short* Xg = side ? Xi : Xu;
            const short8 hv = *(const short8*)(Xg + (size_t)(r0 + row) * 256 + c8);
            const int byte = side * 8192 + row * 512 + ((c8 * 2) ^ ((row & 7) << 4));
            *(short8*)((char*)XsE + byte) = hv;
        }
        __syncthreads();

        const int cwbase = w * 64;
        for (int side = 0; side < 2; ++side) {
            const short* W0l = W0h + side * 65536;
            const short* W1l = W1h + side * 65536;

            f32x4 acc[4];
#pragma unroll
            for (int n = 0; n < 4; ++n) acc[n] = (f32x4){0.f, 0.f, 0.f, 0.f};

            // layer 0 (A rows = 16 tile rows)
#pragma unroll
            for (int ks = 0; ks < 8; ++ks) {
                const int row = l15;
                const int kb  = ks * 64 + l4 * 16;
                const short8 a = *(const short8*)((const char*)XsE + side * 8192 + row * 512 + (kb ^ ((row & 7) << 4)));
#pragma unroll
                for (int n = 0; n < 4; ++n) {
                    const short8 bb = *(const short8*)(W0l + (size_t)(cwbase + n * 16 + l15) * 256 + ks * 32 + l4 * 8);
                    acc[n] = __builtin_amdgcn_mfma_f32_16x16x32_bf16(a, bb, acc[n], 0, 0, 0);
                }
            }
            __syncthreads();   // Hs free (side 1: side 0's layer-1 reads done)

            // bias + relu -> Hs
#pragma unroll
            for (int n = 0; n < 4; ++n) {
                const int col = cwbase + n * 16 + l15;
                const float bia = beff0[side * 256 + col];
#pragma unroll
                for (int r = 0; r < 4; ++r) {
                    const float v = fmaxf(acc[n][r] + bia, 0.f);
                    const int row = l4 * 4 + r;
                    const int byte = row * 512 + ((col * 2) ^ ((row & 7) << 4));
                    *(short*)((char*)Hs + byte) = f2bf(v);
                }
            }
            __syncthreads();

            // layer 1
#pragma unroll
            for (int n = 0; n < 4; ++n) acc[n] = (f32x4){0.f, 0.f, 0.f, 0.f};
#pragma unroll
            for (int ks = 0; ks < 8; ++ks) {
                const int row = l15;
                const int kb  = ks * 64 + l4 * 16;
                const short8 a = *(const short8*)((const char*)Hs + row * 512 + (kb ^ ((row & 7) << 4)));
#pragma unroll
                for (int n = 0; n < 4; ++n) {
                    const short8 bb = *(const short8*)(W1l + (size_t)(cwbase + n * 16 + l15) * 256 + ks * 32 + l4 * 8);
                    acc[n] = __builtin_amdgcn_mfma_f32_16x16x32_bf16(a, bb, acc[n], 0, 0, 0);
                }
            }

            // gate partials
            float w2v[4], b1v[4];
#pragma unroll
            for (int n = 0; n < 4; ++n) {
                const int col = cwbase + n * 16 + l15;
                w2v[n] = w2eff[side * 256 + col];
                b1v[n] = beff1[side * 256 + col];
            }
#pragma unroll
            for (int r = 0; r < 4; ++r) {
                float s = fmaxf(acc[0][r] + b1v[0], 0.f) * w2v[0]
                        + fmaxf(acc[1][r] + b1v[1], 0.f) * w2v[1]
                        + fmaxf(acc[2][r] + b1v[2], 0.f) * w2v[2]
                        + fmaxf(acc[3][r] + b1v[3], 0.f) * w2v[3];
                s += __shfl_xor(s, 1, 16);
                s += __shfl_xor(s, 2, 16);
                s += __shfl_xor(s, 4, 16);
                s += __shfl_xor(s, 8, 16);
                if (l15 == 0) gsum[w][l4 * 4 + r] = s;
            }
            __syncthreads();
            if (tid < 16)
                w_s[side][tid] = 1.0f / (1.0f + expf(-(gsum[0][tid] + gsum[1][tid]
                                 + gsum[2][tid] + gsum[3][tid] + b2eff[side])));
            __syncthreads();
        }

        // fused dot: wave w handles rows w*4 .. w*4+3
        const int d2 = l * 2;
#pragma unroll
        for (int q = 0; q < 4; ++q) {
            const int row = w * 4 + q;
            const int sw = (row & 7) << 4;
            const unsigned ue = *(const unsigned*)((const char*)XsE + row * 512 + ((d2 * 2) ^ sw));
            const unsigned uf = *(const unsigned*)((const char*)XsE + row * 512 + (((128 + d2) * 2) ^ sw));
            const unsigned ie = *(const unsigned*)((const char*)XsE + 8192 + row * 512 + ((d2 * 2) ^ sw));
            const unsigned jf = *(const unsigned*)((const char*)XsE + 8192 + row * 512 + (((128 + d2) * 2) ^ sw));
            const float a = w_s[0][row], c = w_s[1][row];
            const float u0 = a * bf_lo(ue) + (1.f - a) * bf_lo(uf);
            const float u1 = a * bf_hi(ue) + (1.f - a) * bf_hi(uf);
            const float v0 = c * bf_lo(ie) + (1.f - c) * bf_lo(jf);
            const float v1 = c * bf_hi(ie) + (1.f - c) * bf_hi(jf);
            float s = u0 * v0 + u1 * v1;
#pragma unroll
            for (int off = 32; off > 0; off >>= 1) s += __shfl_xor(s, off, 64);
            if (l == 0) out[r0 + row] = s;
        }
    }
}

// ---------------------------------------------------------------------------
extern "C" void kernel_launch(void* const* d_in, const int* in_sizes, int n_in,
                              void* d_out, int out_size, void* d_ws, size_t ws_size,
                              hipStream_t stream)
{
    const float* embed    = (const float*)d_in[0];
    const float* u_cat_tab= (const float*)d_in[2];
    const float* i_cat_tab= (const float*)d_in[3];
    const float* numW_u   = (const float*)d_in[4];
    const float* numb_u   = (const float*)d_in[5];
    const float* numW_i   = (const float*)d_in[6];
    const float* numb_i   = (const float*)d_in[7];
    const float* W0  = (const float*)d_in[8];
    const float* b0  = (const float*)d_in[9];
    const float* Mw0 = (const float*)d_in[10];
    const float* Mb0 = (const float*)d_in[11];
    const float* W1  = (const float*)d_in[12];
    const float* b1  = (const float*)d_in[13];
    const float* Mw1 = (const float*)d_in[14];
    const float* Mb1 = (const float*)d_in[15];
    const float* W2  = (const float*)d_in[16];
    const float* b2  = (const float*)d_in[17];
    const float* Mw2 = (const float*)d_in[18];
    const float* Mb2 = (const float*)d_in[19];
    const float* u_numf = (const float*)d_in[20];
    const float* i_numf = (const float*)d_in[21];
    const float* A_vals = (const float*)d_in[1];
    const int* A_rows = (const int*)d_in[22];
    const int* A_cols = (const int*)d_in[23];
    const int* u_catf = (const int*)d_in[24];
    const int* i_catf = (const int*)d_in[25];
    const int* u_ids  = (const int*)d_in[26];
    const int* i_ids  = (const int*)d_in[27];
    float* out = (float*)d_out;

    char* ws = (char*)d_ws;
    size_t off = 0;
    auto alloc = [&](size_t bytes) -> void* {
        void* p = ws + off;
        off += (bytes + 255) & ~(size_t)255;
        return p;
    };
    int*   bars    = (int*)  alloc(768);                     // grp[4][32] + root[4][16]
    int*   map     = (int*)  alloc((size_t)NTOT * 4);
    int*   bincnt  = (int*)  alloc((size_t)2 * B * 4);
    int2*  bins    = (int2*) alloc((size_t)2 * B * CAP * 8);
    short* W0h     = (short*)alloc((size_t)2 * 65536 * 2);
    short* W1h     = (short*)alloc((size_t)2 * 65536 * 2);
    float* w2eff   = (float*)alloc(512 * 4);
    float* beff0   = (float*)alloc(512 * 4);
    float* beff1   = (float*)alloc(512 * 4);
    float* b2eff   = (float*)alloc(2 * 4);
    unsigned short* Xu = (unsigned short*)alloc((size_t)B * 256 * 2);
    unsigned short* Xi = (unsigned short*)alloc((size_t)B * 256 * 2);

    // re-zero barrier counters every replay (in-graph)
    hipMemsetAsync(bars, 0, 768, stream);

    mega_kernel<<<NBLK, NTHR, 0, stream>>>(
        bars, map, bincnt, bins, W0h, W1h, w2eff, beff0, beff1, b2eff, Xu, Xi,
        embed, u_cat_tab, i_cat_tab, numW_u, numb_u, numW_i, numb_i,
        W0, b0, Mw0, Mb0, W1, b1, Mw1, Mb1, W2, b2, Mw2, Mb2,
        u_numf, i_numf, A_rows, A_cols, A_vals, u_catf, i_catf,
        u_ids, i_ids, out);
}

// Round 8
// 99.321 us; speedup vs baseline: 4.0055x; 4.0055x over previous
//
#include <hip/hip_runtime.h>
#include <math.h>

#define N_USERS 50000
#define N_ENT   200000
#define NTOT    250000
#define D       128
#define E_EDGES 2000000
#define B       8192
#define NCAT    8
#define NNUM    16
#define CAP     64    // per-slot edge bin capacity (Poisson(8) degree; P(>64)~1e-38)
#define BR      32    // batch rows per MLP block

typedef __attribute__((ext_vector_type(4))) float f32x4;
typedef __attribute__((ext_vector_type(8))) short short8;

__device__ __forceinline__ float sigf(float x) { return 1.0f / (1.0f + expf(-x)); }

// fp32 -> bf16 RNE
__device__ __forceinline__ short f2bf(float f) {
    unsigned u = __float_as_uint(f);
    unsigned r = (u + 0x7FFF + ((u >> 16) & 1)) >> 16;
    return (short)r;
}
__device__ __forceinline__ unsigned pack_bf2(float lo, float hi) {
    return ((unsigned)(unsigned short)f2bf(hi) << 16) | (unsigned short)f2bf(lo);
}
__device__ __forceinline__ float bf_lo(unsigned x) { return __uint_as_float(x << 16); }
__device__ __forceinline__ float bf_hi(unsigned x) { return __uint_as_float(x & 0xFFFF0000u); }
__device__ __forceinline__ float dot4(float4 a, float4 b) {
    return a.x * b.x + a.y * b.y + a.z * b.z + a.w * b.w;
}

// ---------------------------------------------------------------------------
// Fused init: map=-1 (62500 int4), bincnt=0 (4096 int4), masked effective weights.
__global__ __launch_bounds__(256) void init_weff_kernel(
    int* __restrict__ map, int* __restrict__ bincnt,
    const float* __restrict__ W0, const float* __restrict__ Mw0,
    const float* __restrict__ b0, const float* __restrict__ Mb0,
    const float* __restrict__ W1, const float* __restrict__ Mw1,
    const float* __restrict__ b1, const float* __restrict__ Mb1,
    const float* __restrict__ W2, const float* __restrict__ Mw2,
    const float* __restrict__ b2, const float* __restrict__ Mb2,
    short* __restrict__ W0h, short* __restrict__ W1h, float* __restrict__ w2eff,
    float* __restrict__ beff0, float* __restrict__ beff1, float* __restrict__ b2eff)
{
    int t = blockIdx.x * 256 + threadIdx.x;
    if (t < 62500) {
        ((int4*)map)[t] = make_int4(-1, -1, -1, -1);
        return;
    }
    t -= 62500;
    if (t < 4096) {
        ((int4*)bincnt)[t] = make_int4(0, 0, 0, 0);
        return;
    }
    int i = t - 4096;
    if (i < 131072) {                      // W0h: [2][256][256]
        W0h[i] = f2bf(W0[i & 65535] * sigf(Mw0[i]));
    } else if (i < 262144) {               // W1h
        int ii = i - 131072;
        W1h[ii] = f2bf(W1[ii & 65535] * sigf(Mw1[ii]));
    } else if (i < 262656) {               // w2eff: [2][256]
        int ii = i - 262144;
        w2eff[ii] = W2[ii & 255] * sigf(Mw2[ii]);
    } else if (i < 263168) {               // beff0
        int ii = i - 262656;
        beff0[ii] = b0[ii & 255] * sigf(Mb0[ii]);
    } else if (i < 263680) {               // beff1
        int ii = i - 263168;
        beff1[ii] = b1[ii & 255] * sigf(Mb1[ii]);
    } else if (i < 263682) {               // b2eff
        int ii = i - 263680;
        b2eff[ii] = b2[0] * sigf(Mb2[ii]);
    }
}

// ---------------------------------------------------------------------------
__global__ __launch_bounds__(256) void build_map_kernel(
    const int* __restrict__ uids, const int* __restrict__ iids, int* __restrict__ map)
{
    int b = blockIdx.x * 256 + threadIdx.x;
    if (b < B) {
        atomicMax(&map[uids[b] + N_ENT], b);
        atomicMax(&map[iids[b]], B + b);
    }
}

// ---------------------------------------------------------------------------
// 2 edges per thread; matched edges drop (col,val) into their slot's bin.
__global__ __launch_bounds__(256) void scatter_kernel(
    const int* __restrict__ A_rows, const int* __restrict__ A_cols,
    const float* __restrict__ A_vals, const int* __restrict__ map,
    int* __restrict__ bincnt, int2* __restrict__ bins)
{
    const int g = blockIdx.x * 256 + threadIdx.x;
    if (g >= E_EDGES / 2) return;
    const int2 rr = *(const int2*)(A_rows + 2 * g);
    const int s0 = map[rr.x];
    const int s1 = map[rr.y];
    if (s0 >= 0) {
        const int p = atomicAdd(&bincnt[s0], 1);
        if (p < CAP)
            bins[(size_t)s0 * CAP + p] = make_int2(A_cols[2 * g], __float_as_int(A_vals[2 * g]));
    }
    if (s1 >= 0) {
        const int p = atomicAdd(&bincnt[s1], 1);
        if (p < CAP)
            bins[(size_t)s1 * CAP + p] = make_int2(A_cols[2 * g + 1], __float_as_int(A_vals[2 * g + 1]));
    }
}

// ---------------------------------------------------------------------------
// Fused neighbor-gather + feature build; one (row,side) per 64-lane wave.
// Wave-uniform values forced to SGPR via readfirstlane; first 8 neighbor
// embed loads issued unconditionally (clamped) for 8-deep MLP. X out in bf16.
__global__ __launch_bounds__(256) void build_x_kernel(
    const int* __restrict__ uids, const int* __restrict__ iids,
    const int* __restrict__ u_catf, const int* __restrict__ i_catf,
    const float* __restrict__ u_numf, const float* __restrict__ i_numf,
    const float* __restrict__ u_tab, const float* __restrict__ i_tab,
    const float* __restrict__ numW_u, const float* __restrict__ numb_u,
    const float* __restrict__ numW_i, const float* __restrict__ numb_i,
    const float* __restrict__ embed, const int* __restrict__ map,
    const int* __restrict__ bincnt, const int2* __restrict__ bins,
    unsigned short* __restrict__ Xu, unsigned short* __restrict__ Xi)
{
    const int wid  = (blockIdx.x * 256 + threadIdx.x) >> 6;   // 0..16383
    const int lane = threadIdx.x & 63;
    const int side = wid & 1;
    const int b    = wid >> 1;
    const int d2   = lane * 2;

    const int* ids = side ? iids : uids;
    const int* cat_feats = side ? i_catf : u_catf;
    const float* num_feats = side ? i_numf : u_numf;
    const float* cat_table = side ? i_tab : u_tab;
    const float* numW = side ? numW_i : numW_u;
    const float* numb = side ? numb_i : numb_u;
    unsigned short* Xo = side ? Xi : Xu;

    const int uid  = __builtin_amdgcn_readfirstlane(ids[b]);
    const int grow = uid + (side ? 0 : N_ENT);
    const int slot = __builtin_amdgcn_readfirstlane(map[grow]);
    const int n    = min(__builtin_amdgcn_readfirstlane(bincnt[slot]), CAP);

    const float2 ev0 = *(const float2*)(embed + (size_t)grow * D + d2);
    const int4* bl4 = (const int4*)(bins + (size_t)slot * CAP);
    const int4 ea = bl4[0], eb = bl4[1], ec = bl4[2], ed = bl4[3];
    const int4 cf0 = *(const int4*)(cat_feats + uid * NCAT);
    const int4 cf1 = *(const int4*)(cat_feats + uid * NCAT + 4);
    const float4* nf = (const float4*)(num_feats + (size_t)uid * NNUM);
    const float4 f0 = nf[0], f1 = nf[1], f2v = nf[2], f3 = nf[3];
    const float2 nbv = *(const float2*)(numb + d2);

    float gx = 0.f, gy = 0.f;
    {
        int cc[8]; float vv[8];
        cc[0]=ea.x; vv[0]=__int_as_float(ea.y); cc[1]=ea.z; vv[1]=__int_as_float(ea.w);
        cc[2]=eb.x; vv[2]=__int_as_float(eb.y); cc[3]=eb.z; vv[3]=__int_as_float(eb.w);
        cc[4]=ec.x; vv[4]=__int_as_float(ec.y); cc[5]=ec.z; vv[5]=__int_as_float(ec.w);
        cc[6]=ed.x; vv[6]=__int_as_float(ed.y); cc[7]=ed.z; vv[7]=__int_as_float(ed.w);
        float2 r[8];
#pragma unroll
        for (int j = 0; j < 8; ++j) {
            const int c = (j < n) ? cc[j] : 0;
            r[j] = *(const float2*)(embed + (size_t)c * D + d2);
        }
#pragma unroll
        for (int j = 0; j < 8; ++j) {
            const float v = (j < n) ? vv[j] : 0.f;
            gx += v * r[j].x;
            gy += v * r[j].y;
        }
    }
    const int2* bl = bins + (size_t)slot * CAP;
    for (int j = 8; j < n; j += 2) {
        const int2 c0 = bl[j];
        const bool has1 = (j + 1 < n);
        const int2 c1 = has1 ? bl[j + 1] : make_int2(0, 0);
        const float2 r0 = *(const float2*)(embed + (size_t)c0.x * D + d2);
        const float2 r1 = *(const float2*)(embed + (size_t)c1.x * D + d2);
        const float v0 = __int_as_float(c0.y);
        const float v1 = has1 ? __int_as_float(c1.y) : 0.f;
        gx += v0 * r0.x + v1 * r1.x;
        gy += v0 * r0.y + v1 * r1.y;
    }

    int cid[8] = {cf0.x, cf0.y, cf0.z, cf0.w, cf1.x, cf1.y, cf1.z, cf1.w};
    int cnt = 0;
#pragma unroll
    for (int f = 0; f < 8; ++f) cnt += (cid[f] > 0);
    float2 ct[8];
#pragma unroll
    for (int f = 0; f < 8; ++f)
        ct[f] = *(const float2*)(cat_table + (size_t)cid[f] * D + d2);
    float csx = 0.f, csy = 0.f;
#pragma unroll
    for (int f = 0; f < 8; ++f) { csx += ct[f].x; csy += ct[f].y; }
    const float inv = (cnt > 0) ? (1.0f / (float)cnt) : 0.0f;

    const float4* w0r = (const float4*)(numW + (size_t)d2 * NNUM);
    const float4* w1r = (const float4*)(numW + (size_t)(d2 + 1) * NNUM);
    float na  = nbv.x + dot4(w0r[0], f0) + dot4(w0r[1], f1) + dot4(w0r[2], f2v) + dot4(w0r[3], f3);
    float nb_ = nbv.y + dot4(w1r[0], f0) + dot4(w1r[1], f1) + dot4(w1r[2], f2v) + dot4(w1r[3], f3);

    const float fx = csx * inv + fmaxf(na, 0.f);
    const float fy = csy * inv + fmaxf(nb_, 0.f);

    unsigned short* row = Xo + (size_t)b * 256;
    *(unsigned*)(row + d2)       = pack_bf2(ev0.x + gx, ev0.y + gy);
    *(unsigned*)(row + 128 + d2) = pack_bf2(fx, fy);
}

// ---------------------------------------------------------------------------
// Fused MLP (both sides) + gate + dot. Block: BR=32 rows, 4 waves.
// Per side: H0=relu(X@W0^T+b0); H1=relu(H0@W1^T+b1); w=sigmoid(H1.w2+b2);
// then out[b] = sum_d (wu*eu+(1-wu)*fu)*(wi*ei+(1-wi)*fi) from LDS X tiles.
// X/H LDS bf16, XOR-swizzled (byte ^= (row&7)<<4). Numerics validated R7.
__global__ __launch_bounds__(256) void fused_mlp_dot_kernel(
    const unsigned short* __restrict__ Xu, const unsigned short* __restrict__ Xi,
    const short* __restrict__ W0h, const short* __restrict__ W1h,
    const float* __restrict__ beff0, const float* __restrict__ beff1,
    const float* __restrict__ w2eff, const float* __restrict__ b2eff,
    float* __restrict__ out)
{
    const int r0 = blockIdx.x * BR;

    __shared__ __align__(16) short XsE[2 * BR * 256];   // 32KB: both X tiles
    __shared__ __align__(16) short Hs[BR * 256];        // 16KB: H0 tile
    __shared__ float gsum[4][BR];
    __shared__ float w_s[2][BR];

    const int tid = threadIdx.x;
    const int w   = tid >> 6;
    const int l   = tid & 63;
    const int l15 = l & 15;
    const int l4  = l >> 4;

    // stage both X tiles (bf16, XOR-swizzled): 2048 chunks of 8 elems
#pragma unroll
    for (int i = 0; i < 8; ++i) {
        const int ch   = tid + i * 256;        // 0..2047
        const int side = ch >> 10;             // 1024 chunks per side
        const int c    = ch & 1023;
        const int row  = c >> 5;
        const int c8   = (c & 31) << 3;
        const unsigned short* Xg = side ? Xi : Xu;
        const short8 hv = *(const short8*)(Xg + (size_t)(r0 + row) * 256 + c8);
        const int byte = side * 16384 + row * 512 + ((c8 * 2) ^ ((row & 7) << 4));
        *(short8*)((char*)XsE + byte) = hv;
    }
    __syncthreads();

    const int cwbase = w * 64;
    for (int side = 0; side < 2; ++side) {
        const short* W0l = W0h + side * 65536;
        const short* W1l = W1h + side * 65536;

        f32x4 acc[2][4];
#pragma unroll
        for (int m = 0; m < 2; ++m)
#pragma unroll
            for (int n = 0; n < 4; ++n) acc[m][n] = (f32x4){0.f, 0.f, 0.f, 0.f};

        // layer 0
#pragma unroll
        for (int ks = 0; ks < 8; ++ks) {
            short8 a[2];
#pragma unroll
            for (int m = 0; m < 2; ++m) {
                const int row = m * 16 + l15;
                const int kb  = ks * 64 + l4 * 16;
                a[m] = *(const short8*)((const char*)XsE + side * 16384 + row * 512 + (kb ^ ((row & 7) << 4)));
            }
#pragma unroll
            for (int n = 0; n < 4; ++n) {
                const short8 bb = *(const short8*)(W0l + (size_t)(cwbase + n * 16 + l15) * 256 + ks * 32 + l4 * 8);
                acc[0][n] = __builtin_amdgcn_mfma_f32_16x16x32_bf16(a[0], bb, acc[0][n], 0, 0, 0);
                acc[1][n] = __builtin_amdgcn_mfma_f32_16x16x32_bf16(a[1], bb, acc[1][n], 0, 0, 0);
            }
        }
        __syncthreads();   // Hs free (side 1: side 0's layer-1 reads done)

        // bias + relu -> Hs
#pragma unroll
        for (int n = 0; n < 4; ++n) {
            const int col = cwbase + n * 16 + l15;
            const float bia = beff0[side * 256 + col];
#pragma unroll
            for (int m = 0; m < 2; ++m)
#pragma unroll
                for (int r = 0; r < 4; ++r) {
                    const float v = fmaxf(acc[m][n][r] + bia, 0.f);
                    const int row = m * 16 + l4 * 4 + r;
                    const int byte = row * 512 + ((col * 2) ^ ((row & 7) << 4));
                    *(short*)((char*)Hs + byte) = f2bf(v);
                }
        }
        __syncthreads();

        // layer 1
#pragma unroll
        for (int m = 0; m < 2; ++m)
#pragma unroll
            for (int n = 0; n < 4; ++n) acc[m][n] = (f32x4){0.f, 0.f, 0.f, 0.f};
#pragma unroll
        for (int ks = 0; ks < 8; ++ks) {
            short8 a[2];
#pragma unroll
            for (int m = 0; m < 2; ++m) {
                const int row = m * 16 + l15;
                const int kb  = ks * 64 + l4 * 16;
                a[m] = *(const short8*)((const char*)Hs + row * 512 + (kb ^ ((row & 7) << 4)));
            }
#pragma unroll
            for (int n = 0; n < 4; ++n) {
                const short8 bb = *(const short8*)(W1l + (size_t)(cwbase + n * 16 + l15) * 256 + ks * 32 + l4 * 8);
                acc[0][n] = __builtin_amdgcn_mfma_f32_16x16x32_bf16(a[0], bb, acc[0][n], 0, 0, 0);
                acc[1][n] = __builtin_amdgcn_mfma_f32_16x16x32_bf16(a[1], bb, acc[1][n], 0, 0, 0);
            }
        }

        // gate partials
        float w2v[4], b1v[4];
#pragma unroll
        for (int n = 0; n < 4; ++n) {
            const int col = cwbase + n * 16 + l15;
            w2v[n] = w2eff[side * 256 + col];
            b1v[n] = beff1[side * 256 + col];
        }
#pragma unroll
        for (int m = 0; m < 2; ++m)
#pragma unroll
            for (int r = 0; r < 4; ++r) {
                float s = fmaxf(acc[m][0][r] + b1v[0], 0.f) * w2v[0]
                        + fmaxf(acc[m][1][r] + b1v[1], 0.f) * w2v[1]
                        + fmaxf(acc[m][2][r] + b1v[2], 0.f) * w2v[2]
                        + fmaxf(acc[m][3][r] + b1v[3], 0.f) * w2v[3];
                s += __shfl_xor(s, 1, 16);
                s += __shfl_xor(s, 2, 16);
                s += __shfl_xor(s, 4, 16);
                s += __shfl_xor(s, 8, 16);
                if (l15 == 0) gsum[w][m * 16 + l4 * 4 + r] = s;
            }
        __syncthreads();
        if (tid < BR)
            w_s[side][tid] = 1.0f / (1.0f + expf(-(gsum[0][tid] + gsum[1][tid]
                             + gsum[2][tid] + gsum[3][tid] + b2eff[side])));
        __syncthreads();
    }

    // fused dot: wave w handles rows w*8 .. w*8+7
    const int d2 = l * 2;
#pragma unroll
    for (int q = 0; q < 8; ++q) {
        const int row = w * 8 + q;
        const int sw = (row & 7) << 4;
        const unsigned ue = *(const unsigned*)((const char*)XsE + row * 512 + ((d2 * 2) ^ sw));
        const unsigned uf = *(const unsigned*)((const char*)XsE + row * 512 + (((128 + d2) * 2) ^ sw));
        const unsigned ie = *(const unsigned*)((const char*)XsE + 16384 + row * 512 + ((d2 * 2) ^ sw));
        const unsigned jf = *(const unsigned*)((const char*)XsE + 16384 + row * 512 + (((128 + d2) * 2) ^ sw));
        const float a = w_s[0][row], c = w_s[1][row];
        const float u0 = a * bf_lo(ue) + (1.f - a) * bf_lo(uf);
        const float u1 = a * bf_hi(ue) + (1.f - a) * bf_hi(uf);
        const float v0 = c * bf_lo(ie) + (1.f - c) * bf_lo(jf);
        const float v1 = c * bf_hi(ie) + (1.f - c) * bf_hi(jf);
        float s = u0 * v0 + u1 * v1;
#pragma unroll
        for (int off = 32; off > 0; off >>= 1) s += __shfl_xor(s, off, 64);
        if (l == 0) out[r0 + row] = s;
    }
}

// ---------------------------------------------------------------------------
extern "C" void kernel_launch(void* const* d_in, const int* in_sizes, int n_in,
                              void* d_out, int out_size, void* d_ws, size_t ws_size,
                              hipStream_t stream)
{
    const float* embed    = (const float*)d_in[0];
    const float* A_vals   = (const float*)d_in[1];
    const float* u_cat_tab= (const float*)d_in[2];
    const float* i_cat_tab= (const float*)d_in[3];
    const float* numW_u   = (const float*)d_in[4];
    const float* numb_u   = (const float*)d_in[5];
    const float* numW_i   = (const float*)d_in[6];
    const float* numb_i   = (const float*)d_in[7];
    const float* W0  = (const float*)d_in[8];
    const float* b0  = (const float*)d_in[9];
    const float* Mw0 = (const float*)d_in[10];
    const float* Mb0 = (const float*)d_in[11];
    const float* W1  = (const float*)d_in[12];
    const float* b1  = (const float*)d_in[13];
    const float* Mw1 = (const float*)d_in[14];
    const float* Mb1 = (const float*)d_in[15];
    const float* W2  = (const float*)d_in[16];
    const float* b2  = (const float*)d_in[17];
    const float* Mw2 = (const float*)d_in[18];
    const float* Mb2 = (const float*)d_in[19];
    const float* u_numf = (const float*)d_in[20];
    const float* i_numf = (const float*)d_in[21];
    const int* A_rows = (const int*)d_in[22];
    const int* A_cols = (const int*)d_in[23];
    const int* u_catf = (const int*)d_in[24];
    const int* i_catf = (const int*)d_in[25];
    const int* u_ids  = (const int*)d_in[26];
    const int* i_ids  = (const int*)d_in[27];
    float* out = (float*)d_out;

    char* ws = (char*)d_ws;
    size_t off = 0;
    auto alloc = [&](size_t bytes) -> void* {
        void* p = ws + off;
        off += (bytes + 255) & ~(size_t)255;
        return p;
    };
    int*   map     = (int*)  alloc((size_t)NTOT * 4);
    int*   bincnt  = (int*)  alloc((size_t)2 * B * 4);
    int2*  bins    = (int2*) alloc((size_t)2 * B * CAP * 8);
    short* W0h     = (short*)alloc((size_t)2 * 65536 * 2);
    short* W1h     = (short*)alloc((size_t)2 * 65536 * 2);
    float* w2eff   = (float*)alloc(512 * 4);
    float* beff0   = (float*)alloc(512 * 4);
    float* beff1   = (float*)alloc(512 * 4);
    float* b2eff   = (float*)alloc(2 * 4);
    unsigned short* Xu = (unsigned short*)alloc((size_t)B * 256 * 2);
    unsigned short* Xi = (unsigned short*)alloc((size_t)B * 256 * 2);

    // 1. init (map=-1, bincnt=0) + effective weights
    init_weff_kernel<<<1291, 256, 0, stream>>>(
        map, bincnt,
        W0, Mw0, b0, Mb0, W1, Mw1, b1, Mb1, W2, Mw2, b2, Mb2,
        W0h, W1h, w2eff, beff0, beff1, b2eff);

    // 2. row -> slot map
    build_map_kernel<<<(B + 255) / 256, 256, 0, stream>>>(u_ids, i_ids, map);

    // 3. edge scatter into per-slot bins (2 edges/thread)
    scatter_kernel<<<(E_EDGES / 2 + 255) / 256, 256, 0, stream>>>(
        A_rows, A_cols, A_vals, map, bincnt, bins);

    // 4. fused neighbor-gather + feature build (1 row-side per wave, bf16 out)
    build_x_kernel<<<(2 * B) / 4, 256, 0, stream>>>(
        u_ids, i_ids, u_catf, i_catf, u_numf, i_numf, u_cat_tab, i_cat_tab,
        numW_u, numb_u, numW_i, numb_i, embed, map, bincnt, bins, Xu, Xi);

    // 5. fused both-sides MLP + gate + dot
    fused_mlp_dot_kernel<<<B / BR, 256, 0, stream>>>(
        Xu, Xi, W0h, W1h, beff0, beff1, w2eff, b2eff, out);
}

// Round 9
// 82.168 us; speedup vs baseline: 4.8417x; 1.2087x over previous
//
#include <hip/hip_runtime.h>
#include <math.h>

#define N_USERS 50000
#define N_ENT   200000
#define NTOT    250000
#define D       128
#define E_EDGES 2000000
#define B       8192
#define NCAT    8
#define NNUM    16
#define CAP     64    // per-slot edge bin capacity (Poisson(8) degree; P(>64)~1e-38)
#define BR      32    // batch rows per MLP block

typedef __attribute__((ext_vector_type(4))) float f32x4;
typedef __attribute__((ext_vector_type(8))) short short8;

__device__ __forceinline__ float sigf(float x) { return 1.0f / (1.0f + expf(-x)); }

// fp32 -> bf16 RNE
__device__ __forceinline__ short f2bf(float f) {
    unsigned u = __float_as_uint(f);
    unsigned r = (u + 0x7FFF + ((u >> 16) & 1)) >> 16;
    return (short)r;
}
__device__ __forceinline__ unsigned pack_bf2(float lo, float hi) {
    return ((unsigned)(unsigned short)f2bf(hi) << 16) | (unsigned short)f2bf(lo);
}
__device__ __forceinline__ float bf_lo(unsigned x) { return __uint_as_float(x << 16); }
__device__ __forceinline__ float bf_hi(unsigned x) { return __uint_as_float(x & 0xFFFF0000u); }
__device__ __forceinline__ float dot4(float4 a, float4 b) {
    return a.x * b.x + a.y * b.y + a.z * b.z + a.w * b.w;
}

// ---------------------------------------------------------------------------
// Single prep dispatch: bincnt=0 (4096 int4), map stores for the batch rows
// (plain racy stores; any winner is a valid canonical slot — scatter
// back-validates against ids, so NO map init fill is needed), and the masked
// effective weights. Thread layout: [0,4096) bincnt | [4096,12288) map |
// [12288, 12288+263682) weff.
__global__ __launch_bounds__(256) void prep_kernel(
    int* __restrict__ map, int* __restrict__ bincnt,
    const int* __restrict__ uids, const int* __restrict__ iids,
    const float* __restrict__ W0, const float* __restrict__ Mw0,
    const float* __restrict__ b0, const float* __restrict__ Mb0,
    const float* __restrict__ W1, const float* __restrict__ Mw1,
    const float* __restrict__ b1, const float* __restrict__ Mb1,
    const float* __restrict__ W2, const float* __restrict__ Mw2,
    const float* __restrict__ b2, const float* __restrict__ Mb2,
    short* __restrict__ W0h, short* __restrict__ W1h, float* __restrict__ w2eff,
    float* __restrict__ beff0, float* __restrict__ beff1, float* __restrict__ b2eff)
{
    int t = blockIdx.x * 256 + threadIdx.x;
    if (t < 4096) {                        // bincnt: 16384 ints
        ((int4*)bincnt)[t] = make_int4(0, 0, 0, 0);
        return;
    }
    t -= 4096;
    if (t < B) {                           // map stores (racy, validate-on-read)
        map[uids[t] + N_ENT] = t;
        map[iids[t]] = B + t;
        return;
    }
    int i = t - B;
    if (i < 131072) {                      // W0h: [2][256][256]
        W0h[i] = f2bf(W0[i & 65535] * sigf(Mw0[i]));
    } else if (i < 262144) {               // W1h
        int ii = i - 131072;
        W1h[ii] = f2bf(W1[ii & 65535] * sigf(Mw1[ii]));
    } else if (i < 262656) {               // w2eff: [2][256]
        int ii = i - 262144;
        w2eff[ii] = W2[ii & 255] * sigf(Mw2[ii]);
    } else if (i < 263168) {               // beff0
        int ii = i - 262656;
        beff0[ii] = b0[ii & 255] * sigf(Mb0[ii]);
    } else if (i < 263680) {               // beff1
        int ii = i - 263168;
        beff1[ii] = b1[ii & 255] * sigf(Mb1[ii]);
    } else if (i < 263682) {               // b2eff
        int ii = i - 263680;
        b2eff[ii] = b2[0] * sigf(Mb2[ii]);
    }
}

// ---------------------------------------------------------------------------
// 2 edges per thread; a map hit counts only if it back-validates against the
// ids arrays (rejects first-replay poison; stale entries from prior replays
// are written from the same static inputs, hence still valid).
__global__ __launch_bounds__(256) void scatter_kernel(
    const int* __restrict__ A_rows, const int* __restrict__ A_cols,
    const float* __restrict__ A_vals, const int* __restrict__ map,
    const int* __restrict__ uids, const int* __restrict__ iids,
    int* __restrict__ bincnt, int2* __restrict__ bins)
{
    const int g = blockIdx.x * 256 + threadIdx.x;
    if (g >= E_EDGES / 2) return;
    const int2 rr = *(const int2*)(A_rows + 2 * g);
    {
        const int slot = map[rr.x];
        bool ok = (unsigned)slot < 2u * B;
        if (ok) {
            const int back = (slot < B) ? (uids[slot] + N_ENT) : iids[slot - B];
            ok = (back == rr.x);
        }
        if (ok) {
            const int p = atomicAdd(&bincnt[slot], 1);
            if (p < CAP)
                bins[(size_t)slot * CAP + p] = make_int2(A_cols[2 * g], __float_as_int(A_vals[2 * g]));
        }
    }
    {
        const int slot = map[rr.y];
        bool ok = (unsigned)slot < 2u * B;
        if (ok) {
            const int back = (slot < B) ? (uids[slot] + N_ENT) : iids[slot - B];
            ok = (back == rr.y);
        }
        if (ok) {
            const int p = atomicAdd(&bincnt[slot], 1);
            if (p < CAP)
                bins[(size_t)slot * CAP + p] = make_int2(A_cols[2 * g + 1], __float_as_int(A_vals[2 * g + 1]));
        }
    }
}

// ---------------------------------------------------------------------------
// Fused neighbor-gather + feature build; one (row,side) per 64-lane wave.
// (R6-verbatim. map[grow] needs no validation: prep rewrites every batch
// row's entry each call.)
__global__ __launch_bounds__(256) void build_x_kernel(
    const int* __restrict__ uids, const int* __restrict__ iids,
    const int* __restrict__ u_catf, const int* __restrict__ i_catf,
    const float* __restrict__ u_numf, const float* __restrict__ i_numf,
    const float* __restrict__ u_tab, const float* __restrict__ i_tab,
    const float* __restrict__ numW_u, const float* __restrict__ numb_u,
    const float* __restrict__ numW_i, const float* __restrict__ numb_i,
    const float* __restrict__ embed, const int* __restrict__ map,
    const int* __restrict__ bincnt, const int2* __restrict__ bins,
    unsigned short* __restrict__ Xu, unsigned short* __restrict__ Xi)
{
    const int wid  = (blockIdx.x * 256 + threadIdx.x) >> 6;   // 0..16383
    const int lane = threadIdx.x & 63;
    const int side = wid & 1;
    const int b    = wid >> 1;
    const int d2   = lane * 2;

    const int* ids = side ? iids : uids;
    const int* cat_feats = side ? i_catf : u_catf;
    const float* num_feats = side ? i_numf : u_numf;
    const float* cat_table = side ? i_tab : u_tab;
    const float* numW = side ? numW_i : numW_u;
    const float* numb = side ? numb_i : numb_u;
    unsigned short* Xo = side ? Xi : Xu;

    const int uid  = __builtin_amdgcn_readfirstlane(ids[b]);
    const int grow = uid + (side ? 0 : N_ENT);
    const int slot = __builtin_amdgcn_readfirstlane(map[grow]);
    const int n    = min(__builtin_amdgcn_readfirstlane(bincnt[slot]), CAP);

    const float2 ev0 = *(const float2*)(embed + (size_t)grow * D + d2);
    const int4* bl4 = (const int4*)(bins + (size_t)slot * CAP);
    const int4 ea = bl4[0], eb = bl4[1], ec = bl4[2], ed = bl4[3];
    const int4 cf0 = *(const int4*)(cat_feats + uid * NCAT);
    const int4 cf1 = *(const int4*)(cat_feats + uid * NCAT + 4);
    const float4* nf = (const float4*)(num_feats + (size_t)uid * NNUM);
    const float4 f0 = nf[0], f1 = nf[1], f2v = nf[2], f3 = nf[3];
    const float2 nbv = *(const float2*)(numb + d2);

    float gx = 0.f, gy = 0.f;
    {
        int cc[8]; float vv[8];
        cc[0]=ea.x; vv[0]=__int_as_float(ea.y); cc[1]=ea.z; vv[1]=__int_as_float(ea.w);
        cc[2]=eb.x; vv[2]=__int_as_float(eb.y); cc[3]=eb.z; vv[3]=__int_as_float(eb.w);
        cc[4]=ec.x; vv[4]=__int_as_float(ec.y); cc[5]=ec.z; vv[5]=__int_as_float(ec.w);
        cc[6]=ed.x; vv[6]=__int_as_float(ed.y); cc[7]=ed.z; vv[7]=__int_as_float(ed.w);
        float2 r[8];
#pragma unroll
        for (int j = 0; j < 8; ++j) {
            const int c = (j < n) ? cc[j] : 0;
            r[j] = *(const float2*)(embed + (size_t)c * D + d2);
        }
#pragma unroll
        for (int j = 0; j < 8; ++j) {
            const float v = (j < n) ? vv[j] : 0.f;
            gx += v * r[j].x;
            gy += v * r[j].y;
        }
    }
    const int2* bl = bins + (size_t)slot * CAP;
    for (int j = 8; j < n; j += 2) {
        const int2 c0 = bl[j];
        const bool has1 = (j + 1 < n);
        const int2 c1 = has1 ? bl[j + 1] : make_int2(0, 0);
        const float2 r0 = *(const float2*)(embed + (size_t)c0.x * D + d2);
        const float2 r1 = *(const float2*)(embed + (size_t)c1.x * D + d2);
        const float v0 = __int_as_float(c0.y);
        const float v1 = has1 ? __int_as_float(c1.y) : 0.f;
        gx += v0 * r0.x + v1 * r1.x;
        gy += v0 * r0.y + v1 * r1.y;
    }

    int cid[8] = {cf0.x, cf0.y, cf0.z, cf0.w, cf1.x, cf1.y, cf1.z, cf1.w};
    int cnt = 0;
#pragma unroll
    for (int f = 0; f < 8; ++f) cnt += (cid[f] > 0);
    float2 ct[8];
#pragma unroll
    for (int f = 0; f < 8; ++f)
        ct[f] = *(const float2*)(cat_table + (size_t)cid[f] * D + d2);
    float csx = 0.f, csy = 0.f;
#pragma unroll
    for (int f = 0; f < 8; ++f) { csx += ct[f].x; csy += ct[f].y; }
    const float inv = (cnt > 0) ? (1.0f / (float)cnt) : 0.0f;

    const float4* w0r = (const float4*)(numW + (size_t)d2 * NNUM);
    const float4* w1r = (const float4*)(numW + (size_t)(d2 + 1) * NNUM);
    float na  = nbv.x + dot4(w0r[0], f0) + dot4(w0r[1], f1) + dot4(w0r[2], f2v) + dot4(w0r[3], f3);
    float nb_ = nbv.y + dot4(w1r[0], f0) + dot4(w1r[1], f1) + dot4(w1r[2], f2v) + dot4(w1r[3], f3);

    const float fx = csx * inv + fmaxf(na, 0.f);
    const float fy = csy * inv + fmaxf(nb_, 0.f);

    unsigned short* row = Xo + (size_t)b * 256;
    *(unsigned*)(row + d2)       = pack_bf2(ev0.x + gx, ev0.y + gy);
    *(unsigned*)(row + 128 + d2) = pack_bf2(fx, fy);
}

// ---------------------------------------------------------------------------
// Fused MLP (bf16 X input), R6-verbatim: H0=relu(X@W0^T+b0);
// H1=relu(H0@W1^T+b1); w=sigmoid(H1.w2+b2). BR=32 rows x 256 cols, 4 waves.
__global__ __launch_bounds__(256) void fused_mlp_kernel(
    const unsigned short* __restrict__ Xu, const unsigned short* __restrict__ Xi,
    const short* __restrict__ W0h, const short* __restrict__ W1h,
    const float* __restrict__ beff0, const float* __restrict__ beff1,
    const float* __restrict__ w2eff, const float* __restrict__ b2eff,
    float* __restrict__ w_u, float* __restrict__ w_i)
{
    const int side = blockIdx.y;               // == task
    const unsigned short* Xg = side ? Xi : Xu;
    float* wout = side ? w_i : w_u;
    const int b0 = blockIdx.x * BR;

    __shared__ __align__(16) short Xs[BR * 256];   // 16KB swizzled bf16
    __shared__ float gsum[4][BR];

    const int tid = threadIdx.x;
    const int w   = tid >> 6;
    const int l   = tid & 63;
    const int l15 = l & 15;
    const int l4  = l >> 4;

    // ---- stage X tile (bf16 global -> bf16 LDS, swizzled) ----
#pragma unroll
    for (int i = 0; i < 4; ++i) {
        const int ch  = tid + i * 256;
        const int row = ch >> 5;
        const int c8  = (ch & 31) << 3;
        const short8 hv = *(const short8*)(Xg + (size_t)(b0 + row) * 256 + c8);
        const int byte = row * 512 + ((c8 * 2) ^ ((row & 7) << 4));
        *(short8*)((char*)Xs + byte) = hv;
    }
    __syncthreads();

    const short* W0l = W0h + (size_t)side * 65536;
    const short* W1l = W1h + (size_t)side * 65536;
    const int cwbase = w * 64;

    f32x4 acc[2][4];
#pragma unroll
    for (int m = 0; m < 2; ++m)
#pragma unroll
        for (int n = 0; n < 4; ++n) acc[m][n] = (f32x4){0.f, 0.f, 0.f, 0.f};

    // ---------------- layer 0 ----------------
#pragma unroll
    for (int ks = 0; ks < 8; ++ks) {
        short8 a[2];
#pragma unroll
        for (int m = 0; m < 2; ++m) {
            const int row = m * 16 + l15;
            const int kb  = ks * 64 + l4 * 16;
            a[m] = *(const short8*)((const char*)Xs + row * 512 + (kb ^ ((row & 7) << 4)));
        }
#pragma unroll
        for (int n = 0; n < 4; ++n) {
            const short8 bb = *(const short8*)(W0l + (size_t)(cwbase + n * 16 + l15) * 256 + ks * 32 + l4 * 8);
            acc[0][n] = __builtin_amdgcn_mfma_f32_16x16x32_bf16(a[0], bb, acc[0][n], 0, 0, 0);
            acc[1][n] = __builtin_amdgcn_mfma_f32_16x16x32_bf16(a[1], bb, acc[1][n], 0, 0, 0);
        }
    }
    __syncthreads();

    // bias + relu, write H0 back into Xs (bf16, same swizzle)
#pragma unroll
    for (int n = 0; n < 4; ++n) {
        const int col = cwbase + n * 16 + l15;
        const float bia = beff0[side * 256 + col];
#pragma unroll
        for (int m = 0; m < 2; ++m)
#pragma unroll
            for (int r = 0; r < 4; ++r) {
                const float v = fmaxf(acc[m][n][r] + bia, 0.f);
                const int row = m * 16 + l4 * 4 + r;
                const int byte = row * 512 + ((col * 2) ^ ((row & 7) << 4));
                *(short*)((char*)Xs + byte) = f2bf(v);
            }
    }
    __syncthreads();

    // ---------------- layer 1 ----------------
#pragma unroll
    for (int m = 0; m < 2; ++m)
#pragma unroll
        for (int n = 0; n < 4; ++n) acc[m][n] = (f32x4){0.f, 0.f, 0.f, 0.f};

#pragma unroll
    for (int ks = 0; ks < 8; ++ks) {
        short8 a[2];
#pragma unroll
        for (int m = 0; m < 2; ++m) {
            const int row = m * 16 + l15;
            const int kb  = ks * 64 + l4 * 16;
            a[m] = *(const short8*)((const char*)Xs + row * 512 + (kb ^ ((row & 7) << 4)));
        }
#pragma unroll
        for (int n = 0; n < 4; ++n) {
            const short8 bb = *(const short8*)(W1l + (size_t)(cwbase + n * 16 + l15) * 256 + ks * 32 + l4 * 8);
            acc[0][n] = __builtin_amdgcn_mfma_f32_16x16x32_bf16(a[0], bb, acc[0][n], 0, 0, 0);
            acc[1][n] = __builtin_amdgcn_mfma_f32_16x16x32_bf16(a[1], bb, acc[1][n], 0, 0, 0);
        }
    }

    // ---------------- gate ----------------
    float w2v[4], b1v[4];
#pragma unroll
    for (int n = 0; n < 4; ++n) {
        const int col = cwbase + n * 16 + l15;
        w2v[n] = w2eff[side * 256 + col];
        b1v[n] = beff1[side * 256 + col];
    }
#pragma unroll
    for (int m = 0; m < 2; ++m)
#pragma unroll
        for (int r = 0; r < 4; ++r) {
            float s = fmaxf(acc[m][0][r] + b1v[0], 0.f) * w2v[0]
                    + fmaxf(acc[m][1][r] + b1v[1], 0.f) * w2v[1]
                    + fmaxf(acc[m][2][r] + b1v[2], 0.f) * w2v[2]
                    + fmaxf(acc[m][3][r] + b1v[3], 0.f) * w2v[3];
            s += __shfl_xor(s, 1, 16);
            s += __shfl_xor(s, 2, 16);
            s += __shfl_xor(s, 4, 16);
            s += __shfl_xor(s, 8, 16);
            if (l15 == 0) gsum[w][m * 16 + l4 * 4 + r] = s;
        }
    __syncthreads();
    if (tid < BR) {
        const float s = gsum[0][tid] + gsum[1][tid] + gsum[2][tid] + gsum[3][tid]
                      + b2eff[side];
        wout[b0 + tid] = 1.0f / (1.0f + expf(-s));
    }
}

// ---------------------------------------------------------------------------
// out[b] = sum_d (wu*eu + (1-wu)*fu) * (wi*ei + (1-wi)*fi), bf16 X inputs.
__global__ __launch_bounds__(256) void dot_kernel(
    const unsigned short* __restrict__ Xu, const unsigned short* __restrict__ Xi,
    const float* __restrict__ wu, const float* __restrict__ wi,
    float* __restrict__ out)
{
    const int tid = threadIdx.x;
    const int wv = tid >> 6, lane = tid & 63;
    const int b = blockIdx.x * 4 + wv;
    const float a = wu[b], c = wi[b];
    const unsigned short* xu = Xu + (size_t)b * 256;
    const unsigned short* xi = Xi + (size_t)b * 256;
    const unsigned ue = *(const unsigned*)(xu + 2 * lane);
    const unsigned uf = *(const unsigned*)(xu + 128 + 2 * lane);
    const unsigned ie = *(const unsigned*)(xi + 2 * lane);
    const unsigned jf = *(const unsigned*)(xi + 128 + 2 * lane);
    const float u0 = a * bf_lo(ue) + (1.f - a) * bf_lo(uf);
    const float u1 = a * bf_hi(ue) + (1.f - a) * bf_hi(uf);
    const float v0 = c * bf_lo(ie) + (1.f - c) * bf_lo(jf);
    const float v1 = c * bf_hi(ie) + (1.f - c) * bf_hi(jf);
    float s = u0 * v0 + u1 * v1;
#pragma unroll
    for (int off = 32; off > 0; off >>= 1) s += __shfl_xor(s, off, 64);
    if (lane == 0) out[b] = s;
}

// ---------------------------------------------------------------------------
extern "C" void kernel_launch(void* const* d_in, const int* in_sizes, int n_in,
                              void* d_out, int out_size, void* d_ws, size_t ws_size,
                              hipStream_t stream)
{
    const float* embed    = (const float*)d_in[0];
    const float* A_vals   = (const float*)d_in[1];
    const float* u_cat_tab= (const float*)d_in[2];
    const float* i_cat_tab= (const float*)d_in[3];
    const float* numW_u   = (const float*)d_in[4];
    const float* numb_u   = (const float*)d_in[5];
    const float* numW_i   = (const float*)d_in[6];
    const float* numb_i   = (const float*)d_in[7];
    const float* W0  = (const float*)d_in[8];
    const float* b0  = (const float*)d_in[9];
    const float* Mw0 = (const float*)d_in[10];
    const float* Mb0 = (const float*)d_in[11];
    const float* W1  = (const float*)d_in[12];
    const float* b1  = (const float*)d_in[13];
    const float* Mw1 = (const float*)d_in[14];
    const float* Mb1 = (const float*)d_in[15];
    const float* W2  = (const float*)d_in[16];
    const float* b2  = (const float*)d_in[17];
    const float* Mw2 = (const float*)d_in[18];
    const float* Mb2 = (const float*)d_in[19];
    const float* u_numf = (const float*)d_in[20];
    const float* i_numf = (const float*)d_in[21];
    const int* A_rows = (const int*)d_in[22];
    const int* A_cols = (const int*)d_in[23];
    const int* u_catf = (const int*)d_in[24];
    const int* i_catf = (const int*)d_in[25];
    const int* u_ids  = (const int*)d_in[26];
    const int* i_ids  = (const int*)d_in[27];
    float* out = (float*)d_out;

    char* ws = (char*)d_ws;
    size_t off = 0;
    auto alloc = [&](size_t bytes) -> void* {
        void* p = ws + off;
        off += (bytes + 255) & ~(size_t)255;
        return p;
    };
    int*   map     = (int*)  alloc((size_t)NTOT * 4);
    int*   bincnt  = (int*)  alloc((size_t)2 * B * 4);
    int2*  bins    = (int2*) alloc((size_t)2 * B * CAP * 8);
    short* W0h     = (short*)alloc((size_t)2 * 65536 * 2);
    short* W1h     = (short*)alloc((size_t)2 * 65536 * 2);
    float* w2eff   = (float*)alloc(512 * 4);
    float* beff0   = (float*)alloc(512 * 4);
    float* beff1   = (float*)alloc(512 * 4);
    float* b2eff   = (float*)alloc(2 * 4);
    unsigned short* Xu = (unsigned short*)alloc((size_t)B * 256 * 2);
    unsigned short* Xi = (unsigned short*)alloc((size_t)B * 256 * 2);
    float* w_u     = (float*)alloc((size_t)B * 4);
    float* w_i     = (float*)alloc((size_t)B * 4);

    // 1. prep: bincnt=0, map stores (validate-on-read; no init fill), weff
    const int prep_threads = 4096 + B + 263682;
    prep_kernel<<<(prep_threads + 255) / 256, 256, 0, stream>>>(
        map, bincnt, u_ids, i_ids,
        W0, Mw0, b0, Mb0, W1, Mw1, b1, Mb1, W2, Mw2, b2, Mb2,
        W0h, W1h, w2eff, beff0, beff1, b2eff);

    // 2. edge scatter into per-slot bins (2 edges/thread, back-validated map)
    scatter_kernel<<<(E_EDGES / 2 + 255) / 256, 256, 0, stream>>>(
        A_rows, A_cols, A_vals, map, u_ids, i_ids, bincnt, bins);

    // 3. fused neighbor-gather + feature build (1 row-side per wave, bf16 out)
    build_x_kernel<<<(2 * B) / 4, 256, 0, stream>>>(
        u_ids, i_ids, u_catf, i_catf, u_numf, i_numf, u_cat_tab, i_cat_tab,
        numW_u, numb_u, numW_i, numb_i, embed, map, bincnt, bins, Xu, Xi);

    // 4. fused 2-layer MFMA MLP + gate
    dim3 mgrid(B / BR, 2);
    fused_mlp_kernel<<<mgrid, 256, 0, stream>>>(
        Xu, Xi, W0h, W1h, beff0, beff1, w2eff, b2eff, w_u, w_i);

    // 5. final gated dot
    dot_kernel<<<B / 4, 256, 0, stream>>>(Xu, Xi, w_u, w_i, out);
}